// Round 5
// baseline (448.918 us; speedup 1.0000x reference)
//
#include <hip/hip_runtime.h>
#include <hip/hip_bf16.h>

#define NN 100000
#define NE 1600000
#define NPART 8

// ---------------- fp32 -> bf16 copy (for gather operand) ----------------
__global__ __launch_bounds__(256) void k_to_bf16(const float4* __restrict__ in, ushort4* __restrict__ out, int n4) {
    int i = blockIdx.x * 256 + threadIdx.x;
    if (i < n4) {
        float4 f = in[i];
        __hip_bfloat16 a = __float2bfloat16(f.x), b = __float2bfloat16(f.y),
                       c = __float2bfloat16(f.z), d = __float2bfloat16(f.w);
        ushort4 u;
        u.x = *(unsigned short*)&a; u.y = *(unsigned short*)&b;
        u.z = *(unsigned short*)&c; u.w = *(unsigned short*)&d;
        out[i] = u;
    }
}

// ---------------- degree count + per-edge rank, 8-way privatized ----------------
__global__ __launch_bounds__(256) void k_count_rank(const int* __restrict__ dst, int* __restrict__ degp,
                                                    unsigned short* __restrict__ rank) {
    int p = blockIdx.x & (NPART - 1);
    int* mydeg = degp + (size_t)p * NN;
    int base = blockIdx.x * 1024 + threadIdx.x;
#pragma unroll
    for (int k = 0; k < 4; k++) {
        int i = base + k * 256;
        if (i < NE) {
            int r = atomicAdd(&mydeg[dst[i]], 1);
            rank[i] = (unsigned short)r;
        }
    }
}

// ---------------- 3-phase exclusive scan over total degree ----------------
__global__ __launch_bounds__(256) void k_scan_partial(const int* __restrict__ degp, int* __restrict__ partial) {
    __shared__ int sd[256];
    int i = blockIdx.x * 256 + threadIdx.x;
    int v = 0;
    if (i < NN) {
#pragma unroll
        for (int p = 0; p < NPART; p++) v += degp[(size_t)p * NN + i];
    }
    sd[threadIdx.x] = v;
    __syncthreads();
    for (int s = 128; s > 0; s >>= 1) {
        if (threadIdx.x < s) sd[threadIdx.x] += sd[threadIdx.x + s];
        __syncthreads();
    }
    if (threadIdx.x == 0) partial[blockIdx.x] = sd[0];
}

__global__ __launch_bounds__(512) void k_scan_block(int* __restrict__ partial, int nb) {
    __shared__ int s[512];
    int t = threadIdx.x;
    s[t] = (t < nb) ? partial[t] : 0;
    __syncthreads();
    for (int off = 1; off < 512; off <<= 1) {
        int add = (t >= off) ? s[t - off] : 0;
        __syncthreads();
        s[t] += add;
        __syncthreads();
    }
    if (t < nb) partial[t] = s[t];
}

__global__ __launch_bounds__(256) void k_scan_final(const int* __restrict__ degp, const int* __restrict__ partialScan,
                                                   int* __restrict__ offsets, int* __restrict__ pstart,
                                                   float* __restrict__ inv_deg) {
    __shared__ int s[256];
    int b = blockIdx.x, t = threadIdx.x;
    int i = b * 256 + t;
    int dp[NPART];
    int v = 0;
    if (i < NN) {
#pragma unroll
        for (int p = 0; p < NPART; p++) { dp[p] = degp[(size_t)p * NN + i]; v += dp[p]; }
    }
    s[t] = v;
    __syncthreads();
    for (int off = 1; off < 256; off <<= 1) {
        int add = (t >= off) ? s[t - off] : 0;
        __syncthreads();
        s[t] += add;
        __syncthreads();
    }
    if (i < NN) {
        int base = (b > 0) ? partialScan[b - 1] : 0;
        int excl = base + s[t] - v;
        offsets[i] = excl;
        inv_deg[i] = (v > 0) ? (1.0f / (float)v) : 0.0f;
        int run = excl;
#pragma unroll
        for (int p = 0; p < NPART; p++) { pstart[(size_t)p * NN + i] = run; run += dp[p]; }
        if (i == NN - 1) offsets[NN] = excl + v;
    }
}

// ---------------- CSR fill: atomic-free scatter ----------------
__global__ __launch_bounds__(256) void k_fill_csr(const int* __restrict__ src, const int* __restrict__ dst,
                                                  const unsigned short* __restrict__ rank,
                                                  const int* __restrict__ pstart,
                                                  int* __restrict__ sorted_src) {
    int p = blockIdx.x & (NPART - 1);
    const int* mystart = pstart + (size_t)p * NN;
    int base = blockIdx.x * 1024 + threadIdx.x;
#pragma unroll
    for (int k = 0; k < 4; k++) {
        int i = base + k * 256;
        if (i < NE) {
            int d = dst[i];
            int pos = mystart[d] + (int)rank[i];
            sorted_src[pos] = src[i];
        }
    }
}

// ---------------- fused SAGE layer: gather-mean(bf16) -> LDS, dual GEMM, optional head ----------------
// Block: 256 threads = 4 waves, tile = 64 dst-nodes x 64 out-features.
template <bool FUSE_HEAD>
__global__ __launch_bounds__(256, 4) void k_sage_layer(
    const unsigned short* __restrict__ featb,   // bf16 gather source [NN][64]
    const float* __restrict__ root,             // fp32 root features [NN][64]
    const int* __restrict__ ssrc, const int* __restrict__ offsets,
    const float* __restrict__ inv_deg,
    const float* __restrict__ W1, const float* __restrict__ W2,
    const float* __restrict__ bias,
    const float* __restrict__ Wfc, const float* __restrict__ bfc,
    float* __restrict__ out_f32,                // layer1: h1 fp32; layer2(FUSE_HEAD): final out [NN]
    ushort4* __restrict__ out_bf16)             // layer1: h1 bf16 copy; layer2: unused
{
    __shared__ __align__(16) float sA1[64 * 65];
    __shared__ __align__(16) float sA2[64 * 65];
    __shared__ float sB[64];
    __shared__ float sWfc[64];
    __shared__ float sRed[64 * 17];

    int tid = threadIdx.x;
    int i0 = blockIdx.x * 64;
    int wave = tid >> 6, lane = tid & 63;

    // root tile (fp32) -> sA2
    int col4 = (tid & 15) * 4;
#pragma unroll
    for (int rep = 0; rep < 4; rep++) {
        int r = rep * 16 + (tid >> 4);
        int g = i0 + r;
        float4 v = {0, 0, 0, 0};
        if (g < NN) v = *(const float4*)&root[(size_t)g * 64 + col4];
        sA2[r * 65 + col4 + 0] = v.x; sA2[r * 65 + col4 + 1] = v.y;
        sA2[r * 65 + col4 + 2] = v.z; sA2[r * 65 + col4 + 3] = v.w;
    }
    if (tid < 64) {
        sB[tid] = bias[tid];
        sWfc[tid] = FUSE_HEAD ? Wfc[tid] : 0.f;
    }

    // gather-mean (bf16 source, fp32 accumulate) -> sA1; wave w handles nodes w*16..w*16+15
    for (int nn = 0; nn < 16; nn++) {
        int r = wave * 16 + nn;
        int node = i0 + r;
        float res = 0.f;
        if (node < NN) {
            int beg = offsets[node], end = offsets[node + 1];
            float a0 = 0.f, a1 = 0.f, a2 = 0.f, a3 = 0.f;
            int e = beg;
            for (; e + 16 <= end; e += 16) {
                int idx[16];
#pragma unroll
                for (int k = 0; k < 16; k++) idx[k] = ssrc[e + k];
                float v[16];
#pragma unroll
                for (int k = 0; k < 16; k++) {
                    unsigned short u = featb[(size_t)idx[k] * 64 + lane];
                    unsigned int w = ((unsigned int)u) << 16;
                    v[k] = *(float*)&w;
                }
#pragma unroll
                for (int k = 0; k < 16; k += 4) {
                    a0 += v[k]; a1 += v[k + 1]; a2 += v[k + 2]; a3 += v[k + 3];
                }
            }
            for (; e + 4 <= end; e += 4) {
                int i0e = ssrc[e], i1e = ssrc[e + 1], i2e = ssrc[e + 2], i3e = ssrc[e + 3];
                unsigned int w0 = ((unsigned int)featb[(size_t)i0e * 64 + lane]) << 16;
                unsigned int w1 = ((unsigned int)featb[(size_t)i1e * 64 + lane]) << 16;
                unsigned int w2 = ((unsigned int)featb[(size_t)i2e * 64 + lane]) << 16;
                unsigned int w3 = ((unsigned int)featb[(size_t)i3e * 64 + lane]) << 16;
                a0 += *(float*)&w0; a1 += *(float*)&w1; a2 += *(float*)&w2; a3 += *(float*)&w3;
            }
            for (; e < end; e++) {
                unsigned int w0 = ((unsigned int)featb[(size_t)ssrc[e] * 64 + lane]) << 16;
                a0 += *(float*)&w0;
            }
            res = ((a0 + a1) + (a2 + a3)) * inv_deg[node];
        }
        sA1[r * 65 + lane] = res;
    }
    __syncthreads();

    // dual GEMM: relu(sA1@W1 + b + sA2@W2); W streamed from global (L1/L2-resident)
    int tj = tid & 15;
    int ti = tid >> 4;
    float acc[4][4] = {};
    const float4* W1v = (const float4*)W1;
    const float4* W2v = (const float4*)W2;
#pragma unroll 8
    for (int k = 0; k < 64; k++) {
        float4 w1 = W1v[k * 16 + tj];
        float4 w2 = W2v[k * 16 + tj];
#pragma unroll
        for (int d = 0; d < 4; d++) {
            float a1 = sA1[(ti * 4 + d) * 65 + k];
            float a2 = sA2[(ti * 4 + d) * 65 + k];
            acc[d][0] += a1 * w1.x; acc[d][0] += a2 * w2.x;
            acc[d][1] += a1 * w1.y; acc[d][1] += a2 * w2.y;
            acc[d][2] += a1 * w1.z; acc[d][2] += a2 * w2.z;
            acc[d][3] += a1 * w1.w; acc[d][3] += a2 * w2.w;
        }
    }

    if (!FUSE_HEAD) {
#pragma unroll
        for (int d = 0; d < 4; d++) {
            int g = i0 + ti * 4 + d;
            if (g < NN) {
                float4 o;
                o.x = fmaxf(acc[d][0] + sB[tj * 4 + 0], 0.f);
                o.y = fmaxf(acc[d][1] + sB[tj * 4 + 1], 0.f);
                o.z = fmaxf(acc[d][2] + sB[tj * 4 + 2], 0.f);
                o.w = fmaxf(acc[d][3] + sB[tj * 4 + 3], 0.f);
                *(float4*)&out_f32[(size_t)g * 64 + tj * 4] = o;
                __hip_bfloat16 ba = __float2bfloat16(o.x), bb = __float2bfloat16(o.y),
                               bc = __float2bfloat16(o.z), bd = __float2bfloat16(o.w);
                ushort4 u;
                u.x = *(unsigned short*)&ba; u.y = *(unsigned short*)&bb;
                u.z = *(unsigned short*)&bc; u.w = *(unsigned short*)&bd;
                out_bf16[((size_t)g * 64 + tj * 4) >> 2] = u;
            }
        }
    } else {
#pragma unroll
        for (int d = 0; d < 4; d++) {
            float psum = 0.f;
            psum += fmaxf(acc[d][0] + sB[tj * 4 + 0], 0.f) * sWfc[tj * 4 + 0];
            psum += fmaxf(acc[d][1] + sB[tj * 4 + 1], 0.f) * sWfc[tj * 4 + 1];
            psum += fmaxf(acc[d][2] + sB[tj * 4 + 2], 0.f) * sWfc[tj * 4 + 2];
            psum += fmaxf(acc[d][3] + sB[tj * 4 + 3], 0.f) * sWfc[tj * 4 + 3];
            sRed[(ti * 4 + d) * 17 + tj] = psum;
        }
        __syncthreads();
        if (tid < 64) {
            float sum = bfc[0];
#pragma unroll
            for (int c = 0; c < 16; c++) sum += sRed[tid * 17 + c];
            int g = i0 + tid;
            if (g < NN) out_f32[g] = sum;
        }
    }
}

extern "C" void kernel_launch(void* const* d_in, const int* in_sizes, int n_in,
                              void* d_out, int out_size, void* d_ws, size_t ws_size,
                              hipStream_t stream) {
    const float* x   = (const float*)d_in[0];
    const int*   ei  = (const int*)d_in[1];
    const float* Wl1 = (const float*)d_in[2];
    const float* bl1 = (const float*)d_in[3];
    const float* Wr1 = (const float*)d_in[4];
    const float* Wl2 = (const float*)d_in[5];
    const float* bl2 = (const float*)d_in[6];
    const float* Wr2 = (const float*)d_in[7];
    const float* Wfc = (const float*)d_in[8];
    const float* bfc = (const float*)d_in[9];
    float* out = (float*)d_out;

    const int* src = ei;       // edge_index[0]
    const int* dst = ei + NE;  // edge_index[1]

    char* p = (char*)d_ws;
    auto carve = [&](size_t bytes) {
        char* q = p;
        p += (bytes + 255) & ~size_t(255);
        return q;
    };
    int*            offsets = (int*)carve((size_t)(NN + 1) * 4);
    int*            partial = (int*)carve(512 * 4);
    float*          inv_deg = (float*)carve((size_t)NN * 4);
    int*            ssrc    = (int*)carve((size_t)NE * 4);
    unsigned short* xb      = (unsigned short*)carve((size_t)NN * 64 * 2);
    unsigned short* h1b     = (unsigned short*)carve((size_t)NN * 64 * 2);
    float*          h1      = (float*)carve((size_t)NN * 64 * 4);
    // temporaries alias onto h1 (dead before h1 is first written by layer-1):
    int*            degp   = (int*)h1;
    int*            pstart = degp + (size_t)NPART * NN;
    unsigned short* rank   = (unsigned short*)(pstart + (size_t)NPART * NN);

    const int ebl4 = (NE + 1023) / 1024;  // 1563
    const int nbl  = (NN + 255) / 256;    // 391
    const int n4   = NN * 64 / 4;         // 1.6M float4s
    const int tile = (NN + 63) / 64;      // 1563

    k_to_bf16<<<(n4 + 255) / 256, 256, 0, stream>>>((const float4*)x, (ushort4*)xb, n4);
    hipMemsetAsync(degp, 0, (size_t)NPART * NN * 4, stream);
    k_count_rank<<<ebl4, 256, 0, stream>>>(dst, degp, rank);
    k_scan_partial<<<nbl, 256, 0, stream>>>(degp, partial);
    k_scan_block<<<1, 512, 0, stream>>>(partial, nbl);
    k_scan_final<<<nbl, 256, 0, stream>>>(degp, partial, offsets, pstart, inv_deg);
    k_fill_csr<<<ebl4, 256, 0, stream>>>(src, dst, rank, pstart, ssrc);

    // layer 1 (writes h1 fp32 + h1b bf16)
    k_sage_layer<false><<<tile, 256, 0, stream>>>(xb, x, ssrc, offsets, inv_deg,
                                                  Wl1, Wr1, bl1, Wfc, bfc, h1, (ushort4*)h1b);
    // layer 2 + fused head
    k_sage_layer<true><<<tile, 256, 0, stream>>>(h1b, h1, ssrc, offsets, inv_deg,
                                                 Wl2, Wr2, bl2, Wfc, bfc, out, nullptr);
}

// Round 6
// 369.439 us; speedup vs baseline: 1.2151x; 1.2151x over previous
//
#include <hip/hip_runtime.h>
#include <hip/hip_bf16.h>

#define NN 100000
#define NE 1600000
#define NPART 8

// ---------------- fp32 -> bf16 copy (for gather operand) ----------------
__global__ __launch_bounds__(256) void k_to_bf16(const float4* __restrict__ in, ushort4* __restrict__ out, int n4) {
    int i = blockIdx.x * 256 + threadIdx.x;
    if (i < n4) {
        float4 f = in[i];
        __hip_bfloat16 a = __float2bfloat16(f.x), b = __float2bfloat16(f.y),
                       c = __float2bfloat16(f.z), d = __float2bfloat16(f.w);
        ushort4 u;
        u.x = *(unsigned short*)&a; u.y = *(unsigned short*)&b;
        u.z = *(unsigned short*)&c; u.w = *(unsigned short*)&d;
        out[i] = u;
    }
}

// ---------------- degree count + per-edge rank, 8-way privatized ----------------
__global__ __launch_bounds__(256) void k_count_rank(const int* __restrict__ dst, int* __restrict__ degp,
                                                    unsigned short* __restrict__ rank) {
    int p = blockIdx.x & (NPART - 1);
    int* mydeg = degp + (size_t)p * NN;
    int base = blockIdx.x * 1024 + threadIdx.x;
#pragma unroll
    for (int k = 0; k < 4; k++) {
        int i = base + k * 256;
        if (i < NE) {
            int r = atomicAdd(&mydeg[dst[i]], 1);
            rank[i] = (unsigned short)r;
        }
    }
}

// ---------------- 3-phase exclusive scan over total degree ----------------
__global__ __launch_bounds__(256) void k_scan_partial(const int* __restrict__ degp, int* __restrict__ partial) {
    __shared__ int sd[256];
    int i = blockIdx.x * 256 + threadIdx.x;
    int v = 0;
    if (i < NN) {
#pragma unroll
        for (int p = 0; p < NPART; p++) v += degp[(size_t)p * NN + i];
    }
    sd[threadIdx.x] = v;
    __syncthreads();
    for (int s = 128; s > 0; s >>= 1) {
        if (threadIdx.x < s) sd[threadIdx.x] += sd[threadIdx.x + s];
        __syncthreads();
    }
    if (threadIdx.x == 0) partial[blockIdx.x] = sd[0];
}

__global__ __launch_bounds__(512) void k_scan_block(int* __restrict__ partial, int nb) {
    __shared__ int s[512];
    int t = threadIdx.x;
    s[t] = (t < nb) ? partial[t] : 0;
    __syncthreads();
    for (int off = 1; off < 512; off <<= 1) {
        int add = (t >= off) ? s[t - off] : 0;
        __syncthreads();
        s[t] += add;
        __syncthreads();
    }
    if (t < nb) partial[t] = s[t];
}

__global__ __launch_bounds__(256) void k_scan_final(const int* __restrict__ degp, const int* __restrict__ partialScan,
                                                   int* __restrict__ offsets, int* __restrict__ pstart,
                                                   float* __restrict__ inv_deg) {
    __shared__ int s[256];
    int b = blockIdx.x, t = threadIdx.x;
    int i = b * 256 + t;
    int dp[NPART];
    int v = 0;
    if (i < NN) {
#pragma unroll
        for (int p = 0; p < NPART; p++) { dp[p] = degp[(size_t)p * NN + i]; v += dp[p]; }
    }
    s[t] = v;
    __syncthreads();
    for (int off = 1; off < 256; off <<= 1) {
        int add = (t >= off) ? s[t - off] : 0;
        __syncthreads();
        s[t] += add;
        __syncthreads();
    }
    if (i < NN) {
        int base = (b > 0) ? partialScan[b - 1] : 0;
        int excl = base + s[t] - v;
        offsets[i] = excl;
        inv_deg[i] = (v > 0) ? (1.0f / (float)v) : 0.0f;
        int run = excl;
#pragma unroll
        for (int p = 0; p < NPART; p++) { pstart[(size_t)p * NN + i] = run; run += dp[p]; }
        if (i == NN - 1) offsets[NN] = excl + v;
    }
}

// ---------------- CSR fill: atomic-free scatter ----------------
__global__ __launch_bounds__(256) void k_fill_csr(const int* __restrict__ src, const int* __restrict__ dst,
                                                  const unsigned short* __restrict__ rank,
                                                  const int* __restrict__ pstart,
                                                  int* __restrict__ sorted_src) {
    int p = blockIdx.x & (NPART - 1);
    const int* mystart = pstart + (size_t)p * NN;
    int base = blockIdx.x * 1024 + threadIdx.x;
#pragma unroll
    for (int k = 0; k < 4; k++) {
        int i = base + k * 256;
        if (i < NE) {
            int d = dst[i];
            int pos = mystart[d] + (int)rank[i];
            sorted_src[pos] = src[i];
        }
    }
}

// ---------------- mean aggregation: one wave per node, lane = feature, bf16 gather ----------------
__global__ __launch_bounds__(256) void k_aggregate(const unsigned short* __restrict__ featb,
                                                   const int* __restrict__ sorted_src,
                                                   const int* __restrict__ offsets, const float* __restrict__ inv_deg,
                                                   float* __restrict__ out) {
    int node = blockIdx.x * 4 + (threadIdx.x >> 6);
    int lane = threadIdx.x & 63;
    if (node >= NN) return;
    int beg = offsets[node], end = offsets[node + 1];
    float a0 = 0.f, a1 = 0.f, a2 = 0.f, a3 = 0.f;
    int e = beg;

    for (; e + 16 <= end; e += 16) {
        int idx[16];
#pragma unroll
        for (int k = 0; k < 16; k++) idx[k] = sorted_src[e + k];
        unsigned short u[16];
#pragma unroll
        for (int k = 0; k < 16; k++) u[k] = featb[(size_t)idx[k] * 64 + lane];
        float v[16];
#pragma unroll
        for (int k = 0; k < 16; k++) {
            unsigned int w = ((unsigned int)u[k]) << 16;
            v[k] = *(float*)&w;
        }
#pragma unroll
        for (int k = 0; k < 16; k += 4) {
            a0 += v[k]; a1 += v[k + 1]; a2 += v[k + 2]; a3 += v[k + 3];
        }
    }
    for (; e + 4 <= end; e += 4) {
        int i0 = sorted_src[e], i1 = sorted_src[e + 1], i2 = sorted_src[e + 2], i3 = sorted_src[e + 3];
        unsigned int w0 = ((unsigned int)featb[(size_t)i0 * 64 + lane]) << 16;
        unsigned int w1 = ((unsigned int)featb[(size_t)i1 * 64 + lane]) << 16;
        unsigned int w2 = ((unsigned int)featb[(size_t)i2 * 64 + lane]) << 16;
        unsigned int w3 = ((unsigned int)featb[(size_t)i3 * 64 + lane]) << 16;
        a0 += *(float*)&w0; a1 += *(float*)&w1; a2 += *(float*)&w2; a3 += *(float*)&w3;
    }
    for (; e < end; e++) {
        unsigned int w0 = ((unsigned int)featb[(size_t)sorted_src[e] * 64 + lane]) << 16;
        a0 += *(float*)&w0;
    }
    out[(size_t)node * 64 + lane] = ((a0 + a1) + (a2 + a3)) * inv_deg[node];
}

// ---------------- fused dual GEMM: out = relu(A1@W1 + b + A2@W2), optional @Wfc+bfc head ----------------
template <bool FUSE_HEAD>
__global__ __launch_bounds__(256) void k_linear(const float* __restrict__ A1, const float* __restrict__ A2,
                                                const float* __restrict__ W1, const float* __restrict__ W2,
                                                const float* __restrict__ bias,
                                                const float* __restrict__ Wfc, const float* __restrict__ bfc,
                                                float* __restrict__ out, ushort4* __restrict__ out_bf16) {
    __shared__ __align__(16) float sA1[64 * 65];
    __shared__ __align__(16) float sA2[64 * 65];
    __shared__ __align__(16) float sW1[64 * 64];
    __shared__ __align__(16) float sW2[64 * 64];
    __shared__ float sB[64];
    __shared__ float sWfc[64];
    __shared__ float sRed[64 * 17];

    int tid = threadIdx.x;
    int i0 = blockIdx.x * 64;

#pragma unroll
    for (int r = 0; r < 4; r++) {
        int idx = r * 1024 + tid * 4;
        *(float4*)&sW1[idx] = *(const float4*)&W1[idx];
        *(float4*)&sW2[idx] = *(const float4*)&W2[idx];
    }
    if (tid < 64) {
        sB[tid] = bias[tid];
        sWfc[tid] = FUSE_HEAD ? Wfc[tid] : 0.f;
    }

    int col4 = (tid & 15) * 4;
#pragma unroll
    for (int rep = 0; rep < 4; rep++) {
        int r = rep * 16 + (tid >> 4);
        int g = i0 + r;
        float4 v1 = {0, 0, 0, 0}, v2 = {0, 0, 0, 0};
        if (g < NN) {
            v1 = *(const float4*)&A1[(size_t)g * 64 + col4];
            v2 = *(const float4*)&A2[(size_t)g * 64 + col4];
        }
        sA1[r * 65 + col4 + 0] = v1.x; sA1[r * 65 + col4 + 1] = v1.y;
        sA1[r * 65 + col4 + 2] = v1.z; sA1[r * 65 + col4 + 3] = v1.w;
        sA2[r * 65 + col4 + 0] = v2.x; sA2[r * 65 + col4 + 1] = v2.y;
        sA2[r * 65 + col4 + 2] = v2.z; sA2[r * 65 + col4 + 3] = v2.w;
    }
    __syncthreads();

    int tj = tid & 15;
    int ti = tid >> 4;
    float acc[4][4] = {};
    const float4* W1f = (const float4*)sW1;
    const float4* W2f = (const float4*)sW2;
#pragma unroll 8
    for (int k = 0; k < 64; k++) {
        float4 w1 = W1f[k * 16 + tj];
        float4 w2 = W2f[k * 16 + tj];
#pragma unroll
        for (int d = 0; d < 4; d++) {
            float a1 = sA1[(ti * 4 + d) * 65 + k];
            float a2 = sA2[(ti * 4 + d) * 65 + k];
            acc[d][0] += a1 * w1.x; acc[d][0] += a2 * w2.x;
            acc[d][1] += a1 * w1.y; acc[d][1] += a2 * w2.y;
            acc[d][2] += a1 * w1.z; acc[d][2] += a2 * w2.z;
            acc[d][3] += a1 * w1.w; acc[d][3] += a2 * w2.w;
        }
    }

    if (!FUSE_HEAD) {
#pragma unroll
        for (int d = 0; d < 4; d++) {
            int g = i0 + ti * 4 + d;
            if (g < NN) {
                float4 o;
                o.x = fmaxf(acc[d][0] + sB[tj * 4 + 0], 0.f);
                o.y = fmaxf(acc[d][1] + sB[tj * 4 + 1], 0.f);
                o.z = fmaxf(acc[d][2] + sB[tj * 4 + 2], 0.f);
                o.w = fmaxf(acc[d][3] + sB[tj * 4 + 3], 0.f);
                *(float4*)&out[(size_t)g * 64 + tj * 4] = o;
                __hip_bfloat16 ba = __float2bfloat16(o.x), bb = __float2bfloat16(o.y),
                               bc = __float2bfloat16(o.z), bd = __float2bfloat16(o.w);
                ushort4 u;
                u.x = *(unsigned short*)&ba; u.y = *(unsigned short*)&bb;
                u.z = *(unsigned short*)&bc; u.w = *(unsigned short*)&bd;
                out_bf16[((size_t)g * 64 + tj * 4) >> 2] = u;
            }
        }
    } else {
#pragma unroll
        for (int d = 0; d < 4; d++) {
            float psum = 0.f;
            psum += fmaxf(acc[d][0] + sB[tj * 4 + 0], 0.f) * sWfc[tj * 4 + 0];
            psum += fmaxf(acc[d][1] + sB[tj * 4 + 1], 0.f) * sWfc[tj * 4 + 1];
            psum += fmaxf(acc[d][2] + sB[tj * 4 + 2], 0.f) * sWfc[tj * 4 + 2];
            psum += fmaxf(acc[d][3] + sB[tj * 4 + 3], 0.f) * sWfc[tj * 4 + 3];
            sRed[(ti * 4 + d) * 17 + tj] = psum;
        }
        __syncthreads();
        if (tid < 64) {
            float sum = bfc[0];
#pragma unroll
            for (int c = 0; c < 16; c++) sum += sRed[tid * 17 + c];
            int g = i0 + tid;
            if (g < NN) out[g] = sum;
        }
    }
}

extern "C" void kernel_launch(void* const* d_in, const int* in_sizes, int n_in,
                              void* d_out, int out_size, void* d_ws, size_t ws_size,
                              hipStream_t stream) {
    const float* x   = (const float*)d_in[0];
    const int*   ei  = (const int*)d_in[1];
    const float* Wl1 = (const float*)d_in[2];
    const float* bl1 = (const float*)d_in[3];
    const float* Wr1 = (const float*)d_in[4];
    const float* Wl2 = (const float*)d_in[5];
    const float* bl2 = (const float*)d_in[6];
    const float* Wr2 = (const float*)d_in[7];
    const float* Wfc = (const float*)d_in[8];
    const float* bfc = (const float*)d_in[9];
    float* out = (float*)d_out;

    const int* src = ei;       // edge_index[0]
    const int* dst = ei + NE;  // edge_index[1]

    char* p = (char*)d_ws;
    auto carve = [&](size_t bytes) {
        char* q = p;
        p += (bytes + 255) & ~size_t(255);
        return q;
    };
    int*            offsets = (int*)carve((size_t)(NN + 1) * 4);
    int*            partial = (int*)carve(512 * 4);
    float*          inv_deg = (float*)carve((size_t)NN * 4);
    int*            ssrc    = (int*)carve((size_t)NE * 4);
    unsigned short* xb      = (unsigned short*)carve((size_t)NN * 64 * 2);
    unsigned short* h1b     = (unsigned short*)carve((size_t)NN * 64 * 2);
    float*          h1      = (float*)carve((size_t)NN * 64 * 4);
    float*          agg     = (float*)carve((size_t)NN * 64 * 4);
    // temporaries alias onto agg (dead before agg is first written by k_aggregate):
    int*            degp   = (int*)agg;
    int*            pstart = degp + (size_t)NPART * NN;
    unsigned short* rank   = (unsigned short*)(pstart + (size_t)NPART * NN);

    const int ebl4 = (NE + 1023) / 1024;  // 1563
    const int nbl  = (NN + 255) / 256;    // 391
    const int n4   = NN * 64 / 4;
    const int tile = (NN + 63) / 64;      // 1563

    k_to_bf16<<<(n4 + 255) / 256, 256, 0, stream>>>((const float4*)x, (ushort4*)xb, n4);
    hipMemsetAsync(degp, 0, (size_t)NPART * NN * 4, stream);
    k_count_rank<<<ebl4, 256, 0, stream>>>(dst, degp, rank);
    k_scan_partial<<<nbl, 256, 0, stream>>>(degp, partial);
    k_scan_block<<<1, 512, 0, stream>>>(partial, nbl);
    k_scan_final<<<nbl, 256, 0, stream>>>(degp, partial, offsets, pstart, inv_deg);
    k_fill_csr<<<ebl4, 256, 0, stream>>>(src, dst, rank, pstart, ssrc);

    // layer 1: gather bf16 x -> agg (fp32), then dual GEMM (writes h1 fp32 + h1b bf16)
    k_aggregate<<<(NN + 3) / 4, 256, 0, stream>>>(xb, ssrc, offsets, inv_deg, agg);
    k_linear<false><<<tile, 256, 0, stream>>>(agg, x, Wl1, Wr1, bl1, Wfc, bfc, h1, (ushort4*)h1b);
    // layer 2 + fused head
    k_aggregate<<<(NN + 3) / 4, 256, 0, stream>>>(h1b, ssrc, offsets, inv_deg, agg);
    k_linear<true><<<tile, 256, 0, stream>>>(agg, h1, Wl2, Wr2, bl2, Wfc, bfc, out, nullptr);
}

// Round 7
// 319.062 us; speedup vs baseline: 1.4070x; 1.1579x over previous
//
#include <hip/hip_runtime.h>
#include <hip/hip_bf16.h>

#define NN 100000
#define NE 1600000
#define SHIFT 8
#define NBUCK 391   // ceil(NN / 256) dst-buckets, 256 nodes each
#define P1B   391   // pass-1 blocks
#define EPB   4093  // ceil(NE / P1B) edges per pass-1 block

// ---------------- fp32 -> bf16 copy (for gather operand) ----------------
__global__ __launch_bounds__(256) void k_to_bf16(const float4* __restrict__ in, ushort4* __restrict__ out, int n4) {
    int i = blockIdx.x * 256 + threadIdx.x;
    if (i < n4) {
        float4 f = in[i];
        __hip_bfloat16 a = __float2bfloat16(f.x), b = __float2bfloat16(f.y),
                       c = __float2bfloat16(f.z), d = __float2bfloat16(f.w);
        ushort4 u;
        u.x = *(unsigned short*)&a; u.y = *(unsigned short*)&b;
        u.z = *(unsigned short*)&c; u.w = *(unsigned short*)&d;
        out[i] = u;
    }
}

// ---------------- pass 1a: per-block LDS histogram over dst buckets ----------------
__global__ __launch_bounds__(256) void k_p1_hist(const int* __restrict__ dst, int* __restrict__ hist) {
    __shared__ int h[NBUCK];
    int t = threadIdx.x, blk = blockIdx.x;
    for (int i = t; i < NBUCK; i += 256) h[i] = 0;
    __syncthreads();
    int beg = blk * EPB, end = min(beg + EPB, NE);
    for (int e = beg + t; e < end; e += 256) atomicAdd(&h[dst[e] >> SHIFT], 1);
    __syncthreads();
    for (int i = t; i < NBUCK; i += 256) hist[(size_t)i * P1B + blk] = h[i];
}

// ---------------- pass 1b: bucket totals ----------------
__global__ __launch_bounds__(256) void k_bin_total(const int* __restrict__ hist, int* __restrict__ bin_total) {
    __shared__ int sd[256];
    int b = blockIdx.x, t = threadIdx.x;
    int v = 0;
    for (int i = t; i < P1B; i += 256) v += hist[(size_t)b * P1B + i];
    sd[t] = v;
    __syncthreads();
    for (int s = 128; s > 0; s >>= 1) {
        if (t < s) sd[t] += sd[t + s];
        __syncthreads();
    }
    if (t == 0) bin_total[b] = sd[0];
}

// ---------------- pass 1c: exclusive scan of bucket totals -> bucket_start ----------------
__global__ __launch_bounds__(512) void k_bin_base(const int* __restrict__ bin_total, int* __restrict__ bucket_start,
                                                  int* __restrict__ offsets) {
    __shared__ int s[512];
    int t = threadIdx.x;
    int v = (t < NBUCK) ? bin_total[t] : 0;
    s[t] = v;
    __syncthreads();
    for (int off = 1; off < 512; off <<= 1) {
        int add = (t >= off) ? s[t - off] : 0;
        __syncthreads();
        s[t] += add;
        __syncthreads();
    }
    if (t < NBUCK) bucket_start[t] = s[t] - v;
    if (t == 0) { bucket_start[NBUCK] = NE; offsets[NN] = NE; }
}

// ---------------- pass 1d: per-bucket scan over blocks -> cursor bases (in-place on hist) ----------------
__global__ __launch_bounds__(512) void k_cursor_base(int* __restrict__ hist, const int* __restrict__ bucket_start) {
    __shared__ int s[512];
    int b = blockIdx.x, t = threadIdx.x;
    int v = (t < P1B) ? hist[(size_t)b * P1B + t] : 0;
    s[t] = v;
    __syncthreads();
    for (int off = 1; off < 512; off <<= 1) {
        int add = (t >= off) ? s[t - off] : 0;
        __syncthreads();
        s[t] += add;
        __syncthreads();
    }
    if (t < P1B) hist[(size_t)b * P1B + t] = bucket_start[b] + s[t] - v;
}

// ---------------- pass 1e: scatter (src,dst) pairs into bucket-contiguous order, LDS cursors ----------------
__global__ __launch_bounds__(256) void k_p1_scatter(const int* __restrict__ src, const int* __restrict__ dst,
                                                    const int* __restrict__ hist, int2* __restrict__ pairs) {
    __shared__ int cur[NBUCK];
    int t = threadIdx.x, blk = blockIdx.x;
    for (int i = t; i < NBUCK; i += 256) cur[i] = hist[(size_t)i * P1B + blk];
    __syncthreads();
    int beg = blk * EPB, end = min(beg + EPB, NE);
    for (int e = beg + t; e < end; e += 256) {
        int d = dst[e];
        int pos = atomicAdd(&cur[d >> SHIFT], 1);
        pairs[pos] = make_int2(src[e], d);
    }
}

// ---------------- pass 2: per-bucket CSR finalize (LDS count + scan + scatter) ----------------
__global__ __launch_bounds__(256) void k_bucket_csr(const int2* __restrict__ pairs, const int* __restrict__ bucket_start,
                                                    int* __restrict__ ssrc, int* __restrict__ offsets,
                                                    float* __restrict__ inv_deg) {
    __shared__ int cnt[256];
    __shared__ int excl[256];
    int b = blockIdx.x, t = threadIdx.x;
    cnt[t] = 0;
    __syncthreads();
    int beg = bucket_start[b], end = bucket_start[b + 1];
    for (int e = beg + t; e < end; e += 256) atomicAdd(&cnt[pairs[e].y & 255], 1);
    __syncthreads();
    int deg = cnt[t];
    excl[t] = deg;
    __syncthreads();
    for (int off = 1; off < 256; off <<= 1) {
        int add = (t >= off) ? excl[t - off] : 0;
        __syncthreads();
        excl[t] += add;
        __syncthreads();
    }
    int ex = excl[t] - deg;
    int node = (b << SHIFT) + t;
    if (node < NN) {
        offsets[node] = beg + ex;
        inv_deg[node] = (deg > 0) ? (1.0f / (float)deg) : 0.0f;
    }
    __syncthreads();
    cnt[t] = beg + ex;  // cursor
    __syncthreads();
    for (int e = beg + t; e < end; e += 256) {
        int2 pr = pairs[e];
        int pos = atomicAdd(&cnt[pr.y & 255], 1);
        ssrc[pos] = pr.x;
    }
}

// ---------------- mean aggregation: one wave per node, lane = feature, bf16 gather ----------------
__global__ __launch_bounds__(256) void k_aggregate(const unsigned short* __restrict__ featb,
                                                   const int* __restrict__ sorted_src,
                                                   const int* __restrict__ offsets, const float* __restrict__ inv_deg,
                                                   float* __restrict__ out) {
    int node = blockIdx.x * 4 + (threadIdx.x >> 6);
    int lane = threadIdx.x & 63;
    if (node >= NN) return;
    int beg = offsets[node], end = offsets[node + 1];
    float a0 = 0.f, a1 = 0.f, a2 = 0.f, a3 = 0.f;
    int e = beg;

    for (; e + 16 <= end; e += 16) {
        int idx[16];
#pragma unroll
        for (int k = 0; k < 16; k++) idx[k] = sorted_src[e + k];
        unsigned short u[16];
#pragma unroll
        for (int k = 0; k < 16; k++) u[k] = featb[(size_t)idx[k] * 64 + lane];
        float v[16];
#pragma unroll
        for (int k = 0; k < 16; k++) {
            unsigned int w = ((unsigned int)u[k]) << 16;
            v[k] = *(float*)&w;
        }
#pragma unroll
        for (int k = 0; k < 16; k += 4) {
            a0 += v[k]; a1 += v[k + 1]; a2 += v[k + 2]; a3 += v[k + 3];
        }
    }
    for (; e + 4 <= end; e += 4) {
        int i0 = sorted_src[e], i1 = sorted_src[e + 1], i2 = sorted_src[e + 2], i3 = sorted_src[e + 3];
        unsigned int w0 = ((unsigned int)featb[(size_t)i0 * 64 + lane]) << 16;
        unsigned int w1 = ((unsigned int)featb[(size_t)i1 * 64 + lane]) << 16;
        unsigned int w2 = ((unsigned int)featb[(size_t)i2 * 64 + lane]) << 16;
        unsigned int w3 = ((unsigned int)featb[(size_t)i3 * 64 + lane]) << 16;
        a0 += *(float*)&w0; a1 += *(float*)&w1; a2 += *(float*)&w2; a3 += *(float*)&w3;
    }
    for (; e < end; e++) {
        unsigned int w0 = ((unsigned int)featb[(size_t)sorted_src[e] * 64 + lane]) << 16;
        a0 += *(float*)&w0;
    }
    out[(size_t)node * 64 + lane] = ((a0 + a1) + (a2 + a3)) * inv_deg[node];
}

// ---------------- fused dual GEMM: out = relu(A1@W1 + b + A2@W2), optional @Wfc+bfc head ----------------
template <bool FUSE_HEAD>
__global__ __launch_bounds__(256) void k_linear(const float* __restrict__ A1, const float* __restrict__ A2,
                                                const float* __restrict__ W1, const float* __restrict__ W2,
                                                const float* __restrict__ bias,
                                                const float* __restrict__ Wfc, const float* __restrict__ bfc,
                                                float* __restrict__ out, ushort4* __restrict__ out_bf16) {
    __shared__ __align__(16) float sA1[64 * 65];
    __shared__ __align__(16) float sA2[64 * 65];
    __shared__ __align__(16) float sW1[64 * 64];
    __shared__ __align__(16) float sW2[64 * 64];
    __shared__ float sB[64];
    __shared__ float sWfc[64];
    __shared__ float sRed[64 * 17];

    int tid = threadIdx.x;
    int i0 = blockIdx.x * 64;

#pragma unroll
    for (int r = 0; r < 4; r++) {
        int idx = r * 1024 + tid * 4;
        *(float4*)&sW1[idx] = *(const float4*)&W1[idx];
        *(float4*)&sW2[idx] = *(const float4*)&W2[idx];
    }
    if (tid < 64) {
        sB[tid] = bias[tid];
        sWfc[tid] = FUSE_HEAD ? Wfc[tid] : 0.f;
    }

    int col4 = (tid & 15) * 4;
#pragma unroll
    for (int rep = 0; rep < 4; rep++) {
        int r = rep * 16 + (tid >> 4);
        int g = i0 + r;
        float4 v1 = {0, 0, 0, 0}, v2 = {0, 0, 0, 0};
        if (g < NN) {
            v1 = *(const float4*)&A1[(size_t)g * 64 + col4];
            v2 = *(const float4*)&A2[(size_t)g * 64 + col4];
        }
        sA1[r * 65 + col4 + 0] = v1.x; sA1[r * 65 + col4 + 1] = v1.y;
        sA1[r * 65 + col4 + 2] = v1.z; sA1[r * 65 + col4 + 3] = v1.w;
        sA2[r * 65 + col4 + 0] = v2.x; sA2[r * 65 + col4 + 1] = v2.y;
        sA2[r * 65 + col4 + 2] = v2.z; sA2[r * 65 + col4 + 3] = v2.w;
    }
    __syncthreads();

    int tj = tid & 15;
    int ti = tid >> 4;
    float acc[4][4] = {};
    const float4* W1f = (const float4*)sW1;
    const float4* W2f = (const float4*)sW2;
#pragma unroll 8
    for (int k = 0; k < 64; k++) {
        float4 w1 = W1f[k * 16 + tj];
        float4 w2 = W2f[k * 16 + tj];
#pragma unroll
        for (int d = 0; d < 4; d++) {
            float a1 = sA1[(ti * 4 + d) * 65 + k];
            float a2 = sA2[(ti * 4 + d) * 65 + k];
            acc[d][0] += a1 * w1.x; acc[d][0] += a2 * w2.x;
            acc[d][1] += a1 * w1.y; acc[d][1] += a2 * w2.y;
            acc[d][2] += a1 * w1.z; acc[d][2] += a2 * w2.z;
            acc[d][3] += a1 * w1.w; acc[d][3] += a2 * w2.w;
        }
    }

    if (!FUSE_HEAD) {
#pragma unroll
        for (int d = 0; d < 4; d++) {
            int g = i0 + ti * 4 + d;
            if (g < NN) {
                float4 o;
                o.x = fmaxf(acc[d][0] + sB[tj * 4 + 0], 0.f);
                o.y = fmaxf(acc[d][1] + sB[tj * 4 + 1], 0.f);
                o.z = fmaxf(acc[d][2] + sB[tj * 4 + 2], 0.f);
                o.w = fmaxf(acc[d][3] + sB[tj * 4 + 3], 0.f);
                *(float4*)&out[(size_t)g * 64 + tj * 4] = o;
                __hip_bfloat16 ba = __float2bfloat16(o.x), bb = __float2bfloat16(o.y),
                               bc = __float2bfloat16(o.z), bd = __float2bfloat16(o.w);
                ushort4 u;
                u.x = *(unsigned short*)&ba; u.y = *(unsigned short*)&bb;
                u.z = *(unsigned short*)&bc; u.w = *(unsigned short*)&bd;
                out_bf16[((size_t)g * 64 + tj * 4) >> 2] = u;
            }
        }
    } else {
#pragma unroll
        for (int d = 0; d < 4; d++) {
            float psum = 0.f;
            psum += fmaxf(acc[d][0] + sB[tj * 4 + 0], 0.f) * sWfc[tj * 4 + 0];
            psum += fmaxf(acc[d][1] + sB[tj * 4 + 1], 0.f) * sWfc[tj * 4 + 1];
            psum += fmaxf(acc[d][2] + sB[tj * 4 + 2], 0.f) * sWfc[tj * 4 + 2];
            psum += fmaxf(acc[d][3] + sB[tj * 4 + 3], 0.f) * sWfc[tj * 4 + 3];
            sRed[(ti * 4 + d) * 17 + tj] = psum;
        }
        __syncthreads();
        if (tid < 64) {
            float sum = bfc[0];
#pragma unroll
            for (int c = 0; c < 16; c++) sum += sRed[tid * 17 + c];
            int g = i0 + tid;
            if (g < NN) out[g] = sum;
        }
    }
}

extern "C" void kernel_launch(void* const* d_in, const int* in_sizes, int n_in,
                              void* d_out, int out_size, void* d_ws, size_t ws_size,
                              hipStream_t stream) {
    const float* x   = (const float*)d_in[0];
    const int*   ei  = (const int*)d_in[1];
    const float* Wl1 = (const float*)d_in[2];
    const float* bl1 = (const float*)d_in[3];
    const float* Wr1 = (const float*)d_in[4];
    const float* Wl2 = (const float*)d_in[5];
    const float* bl2 = (const float*)d_in[6];
    const float* Wr2 = (const float*)d_in[7];
    const float* Wfc = (const float*)d_in[8];
    const float* bfc = (const float*)d_in[9];
    float* out = (float*)d_out;

    const int* src = ei;       // edge_index[0]
    const int* dst = ei + NE;  // edge_index[1]

    char* p = (char*)d_ws;
    auto carve = [&](size_t bytes) {
        char* q = p;
        p += (bytes + 255) & ~size_t(255);
        return q;
    };
    int*            offsets = (int*)carve((size_t)(NN + 1) * 4);
    float*          inv_deg = (float*)carve((size_t)NN * 4);
    int*            ssrc    = (int*)carve((size_t)NE * 4);
    unsigned short* xb      = (unsigned short*)carve((size_t)NN * 64 * 2);
    unsigned short* h1b     = (unsigned short*)carve((size_t)NN * 64 * 2);
    float*          h1      = (float*)carve((size_t)NN * 64 * 4);
    float*          agg     = (float*)carve((size_t)NN * 64 * 4);
    // temporaries alias onto agg (dead before k_aggregate first writes agg):
    // pairs: NE*8 = 12.8 MB, hist: NBUCK*P1B*4 = 611 KB, bin_total+bucket_start small. Total < 14 MB < 25.6 MB.
    int2* pairs        = (int2*)agg;
    int*  hist         = (int*)(pairs + NE);
    int*  bin_total    = hist + (size_t)NBUCK * P1B;
    int*  bucket_start = bin_total + NBUCK;  // NBUCK+1 ints

    const int n4   = NN * 64 / 4;
    const int tile = (NN + 63) / 64;  // 1563

    k_to_bf16<<<(n4 + 255) / 256, 256, 0, stream>>>((const float4*)x, (ushort4*)xb, n4);

    // graph build: two-level LDS counting sort, zero global atomics
    k_p1_hist<<<P1B, 256, 0, stream>>>(dst, hist);
    k_bin_total<<<NBUCK, 256, 0, stream>>>(hist, bin_total);
    k_bin_base<<<1, 512, 0, stream>>>(bin_total, bucket_start, offsets);
    k_cursor_base<<<NBUCK, 512, 0, stream>>>(hist, bucket_start);
    k_p1_scatter<<<P1B, 256, 0, stream>>>(src, dst, hist, pairs);
    k_bucket_csr<<<NBUCK, 256, 0, stream>>>(pairs, bucket_start, ssrc, offsets, inv_deg);

    // layer 1: gather bf16 x -> agg (fp32), then dual GEMM (writes h1 fp32 + h1b bf16)
    k_aggregate<<<(NN + 3) / 4, 256, 0, stream>>>(xb, ssrc, offsets, inv_deg, agg);
    k_linear<false><<<tile, 256, 0, stream>>>(agg, x, Wl1, Wr1, bl1, Wfc, bfc, h1, (ushort4*)h1b);
    // layer 2 + fused head
    k_aggregate<<<(NN + 3) / 4, 256, 0, stream>>>(h1b, ssrc, offsets, inv_deg, agg);
    k_linear<true><<<tile, 256, 0, stream>>>(agg, h1, Wl2, Wr2, bl2, Wfc, bfc, out, nullptr);
}

// Round 8
// 297.078 us; speedup vs baseline: 1.5111x; 1.0740x over previous
//
#include <hip/hip_runtime.h>
#include <hip/hip_bf16.h>

#define NN 100000
#define NE 1600000
#define SHIFT 8
#define NBUCK 391   // ceil(NN / 256) dst-buckets, 256 nodes each
#define P1B   391   // pass-1 blocks
#define EPB   4093  // ceil(NE / P1B) edges per pass-1 block

// ---------------- fp32 -> bf16 copy (for gather operand) ----------------
__global__ __launch_bounds__(256) void k_to_bf16(const float4* __restrict__ in, ushort4* __restrict__ out, int n4) {
    int i = blockIdx.x * 256 + threadIdx.x;
    if (i < n4) {
        float4 f = in[i];
        __hip_bfloat16 a = __float2bfloat16(f.x), b = __float2bfloat16(f.y),
                       c = __float2bfloat16(f.z), d = __float2bfloat16(f.w);
        ushort4 u;
        u.x = *(unsigned short*)&a; u.y = *(unsigned short*)&b;
        u.z = *(unsigned short*)&c; u.w = *(unsigned short*)&d;
        out[i] = u;
    }
}

// ---------------- pass 1a: per-block LDS histogram over dst buckets ----------------
__global__ __launch_bounds__(256) void k_p1_hist(const int* __restrict__ dst, int* __restrict__ hist) {
    __shared__ int h[NBUCK];
    int t = threadIdx.x, blk = blockIdx.x;
    for (int i = t; i < NBUCK; i += 256) h[i] = 0;
    __syncthreads();
    int beg = blk * EPB, end = min(beg + EPB, NE);
    for (int e = beg + t; e < end; e += 256) atomicAdd(&h[dst[e] >> SHIFT], 1);
    __syncthreads();
    for (int i = t; i < NBUCK; i += 256) hist[(size_t)i * P1B + blk] = h[i];
}

// ---------------- pass 1b: bucket totals ----------------
__global__ __launch_bounds__(256) void k_bin_total(const int* __restrict__ hist, int* __restrict__ bin_total) {
    __shared__ int sd[256];
    int b = blockIdx.x, t = threadIdx.x;
    int v = 0;
    for (int i = t; i < P1B; i += 256) v += hist[(size_t)b * P1B + i];
    sd[t] = v;
    __syncthreads();
    for (int s = 128; s > 0; s >>= 1) {
        if (t < s) sd[t] += sd[t + s];
        __syncthreads();
    }
    if (t == 0) bin_total[b] = sd[0];
}

// ---------------- pass 1c: exclusive scan of bucket totals -> bucket_start ----------------
__global__ __launch_bounds__(512) void k_bin_base(const int* __restrict__ bin_total, int* __restrict__ bucket_start,
                                                  int* __restrict__ offsets) {
    __shared__ int s[512];
    int t = threadIdx.x;
    int v = (t < NBUCK) ? bin_total[t] : 0;
    s[t] = v;
    __syncthreads();
    for (int off = 1; off < 512; off <<= 1) {
        int add = (t >= off) ? s[t - off] : 0;
        __syncthreads();
        s[t] += add;
        __syncthreads();
    }
    if (t < NBUCK) bucket_start[t] = s[t] - v;
    if (t == 0) { bucket_start[NBUCK] = NE; offsets[NN] = NE; }
}

// ---------------- pass 1d: per-bucket scan over blocks -> cursor bases (in-place on hist) ----------------
__global__ __launch_bounds__(512) void k_cursor_base(int* __restrict__ hist, const int* __restrict__ bucket_start) {
    __shared__ int s[512];
    int b = blockIdx.x, t = threadIdx.x;
    int v = (t < P1B) ? hist[(size_t)b * P1B + t] : 0;
    s[t] = v;
    __syncthreads();
    for (int off = 1; off < 512; off <<= 1) {
        int add = (t >= off) ? s[t - off] : 0;
        __syncthreads();
        s[t] += add;
        __syncthreads();
    }
    if (t < P1B) hist[(size_t)b * P1B + t] = bucket_start[b] + s[t] - v;
}

// ---------------- pass 1e: scatter (src,dst) pairs into bucket-contiguous order, LDS cursors ----------------
__global__ __launch_bounds__(256) void k_p1_scatter(const int* __restrict__ src, const int* __restrict__ dst,
                                                    const int* __restrict__ hist, int2* __restrict__ pairs) {
    __shared__ int cur[NBUCK];
    int t = threadIdx.x, blk = blockIdx.x;
    for (int i = t; i < NBUCK; i += 256) cur[i] = hist[(size_t)i * P1B + blk];
    __syncthreads();
    int beg = blk * EPB, end = min(beg + EPB, NE);
    for (int e = beg + t; e < end; e += 256) {
        int d = dst[e];
        int pos = atomicAdd(&cur[d >> SHIFT], 1);
        pairs[pos] = make_int2(src[e], d);
    }
}

// ---------------- pass 2: per-bucket CSR finalize (LDS count + scan + scatter) ----------------
__global__ __launch_bounds__(256) void k_bucket_csr(const int2* __restrict__ pairs, const int* __restrict__ bucket_start,
                                                    int* __restrict__ ssrc, int* __restrict__ offsets,
                                                    float* __restrict__ inv_deg) {
    __shared__ int cnt[256];
    __shared__ int excl[256];
    int b = blockIdx.x, t = threadIdx.x;
    cnt[t] = 0;
    __syncthreads();
    int beg = bucket_start[b], end = bucket_start[b + 1];
    for (int e = beg + t; e < end; e += 256) atomicAdd(&cnt[pairs[e].y & 255], 1);
    __syncthreads();
    int deg = cnt[t];
    excl[t] = deg;
    __syncthreads();
    for (int off = 1; off < 256; off <<= 1) {
        int add = (t >= off) ? excl[t - off] : 0;
        __syncthreads();
        excl[t] += add;
        __syncthreads();
    }
    int ex = excl[t] - deg;
    int node = (b << SHIFT) + t;
    if (node < NN) {
        offsets[node] = beg + ex;
        inv_deg[node] = (deg > 0) ? (1.0f / (float)deg) : 0.0f;
    }
    __syncthreads();
    cnt[t] = beg + ex;  // cursor
    __syncthreads();
    for (int e = beg + t; e < end; e += 256) {
        int2 pr = pairs[e];
        int pos = atomicAdd(&cnt[pr.y & 255], 1);
        ssrc[pos] = pr.x;
    }
}

// ---------------- mean aggregation: one wave per node, 8 edges per wave-request ----------------
// Lane l: chunk c=l&7 (features 8c..8c+7 as uint4 of bf16x8), edge-slot g=l>>3.
// One uint4 gather = 8 neighbor rows x 128B = 1KB per wave instruction.
__device__ __forceinline__ void acc_bf16x8(float* acc, uint4 q) {
    unsigned int lo, hi;
    lo = q.x << 16;        hi = q.x & 0xffff0000u;
    acc[0] += *(float*)&lo; acc[1] += *(float*)&hi;
    lo = q.y << 16;        hi = q.y & 0xffff0000u;
    acc[2] += *(float*)&lo; acc[3] += *(float*)&hi;
    lo = q.z << 16;        hi = q.z & 0xffff0000u;
    acc[4] += *(float*)&lo; acc[5] += *(float*)&hi;
    lo = q.w << 16;        hi = q.w & 0xffff0000u;
    acc[6] += *(float*)&lo; acc[7] += *(float*)&hi;
}

__global__ __launch_bounds__(256) void k_aggregate(const uint4* __restrict__ featq,
                                                   const int* __restrict__ ssrc,
                                                   const int* __restrict__ offsets, const float* __restrict__ inv_deg,
                                                   float* __restrict__ out) {
    int node = blockIdx.x * 4 + (threadIdx.x >> 6);
    int lane = threadIdx.x & 63;
    if (node >= NN) return;
    int c = lane & 7, g = lane >> 3;
    int beg = offsets[node], end = offsets[node + 1];
    float acc[8] = {};
    int e = beg;

    for (; e + 16 <= end; e += 16) {
        int i0 = ssrc[e + g];
        int i1 = ssrc[e + 8 + g];
        uint4 q0 = featq[(size_t)i0 * 8 + c];
        uint4 q1 = featq[(size_t)i1 * 8 + c];
        acc_bf16x8(acc, q0);
        acc_bf16x8(acc, q1);
    }
    for (; e < end; e += 8) {
        int m = end - e;  // 1..8 valid edges
        int idx = ssrc[e + (g < m ? g : m - 1)];
        uint4 q = featq[(size_t)idx * 8 + c];
        if (g < m) acc_bf16x8(acc, q);
    }

    // fold the 8 edge-slots together (lanes differing in bits 3..5)
#pragma unroll
    for (int mask = 8; mask <= 32; mask <<= 1) {
#pragma unroll
        for (int j = 0; j < 8; j++) acc[j] += __shfl_xor(acc[j], mask);
    }

    if (g == 0) {
        float s = inv_deg[node];
        float4 o0 = {acc[0] * s, acc[1] * s, acc[2] * s, acc[3] * s};
        float4 o1 = {acc[4] * s, acc[5] * s, acc[6] * s, acc[7] * s};
        *(float4*)&out[(size_t)node * 64 + c * 8]     = o0;
        *(float4*)&out[(size_t)node * 64 + c * 8 + 4] = o1;
    }
}

// ---------------- fused dual GEMM: out = relu(A1@W1 + b + A2@W2), optional @Wfc+bfc head ----------------
template <bool FUSE_HEAD>
__global__ __launch_bounds__(256) void k_linear(const float* __restrict__ A1, const float* __restrict__ A2,
                                                const float* __restrict__ W1, const float* __restrict__ W2,
                                                const float* __restrict__ bias,
                                                const float* __restrict__ Wfc, const float* __restrict__ bfc,
                                                float* __restrict__ out, ushort4* __restrict__ out_bf16) {
    __shared__ __align__(16) float sA1[64 * 65];
    __shared__ __align__(16) float sA2[64 * 65];
    __shared__ __align__(16) float sW1[64 * 64];
    __shared__ __align__(16) float sW2[64 * 64];
    __shared__ float sB[64];
    __shared__ float sWfc[64];
    __shared__ float sRed[64 * 17];

    int tid = threadIdx.x;
    int i0 = blockIdx.x * 64;

#pragma unroll
    for (int r = 0; r < 4; r++) {
        int idx = r * 1024 + tid * 4;
        *(float4*)&sW1[idx] = *(const float4*)&W1[idx];
        *(float4*)&sW2[idx] = *(const float4*)&W2[idx];
    }
    if (tid < 64) {
        sB[tid] = bias[tid];
        sWfc[tid] = FUSE_HEAD ? Wfc[tid] : 0.f;
    }

    int col4 = (tid & 15) * 4;
#pragma unroll
    for (int rep = 0; rep < 4; rep++) {
        int r = rep * 16 + (tid >> 4);
        int g = i0 + r;
        float4 v1 = {0, 0, 0, 0}, v2 = {0, 0, 0, 0};
        if (g < NN) {
            v1 = *(const float4*)&A1[(size_t)g * 64 + col4];
            v2 = *(const float4*)&A2[(size_t)g * 64 + col4];
        }
        sA1[r * 65 + col4 + 0] = v1.x; sA1[r * 65 + col4 + 1] = v1.y;
        sA1[r * 65 + col4 + 2] = v1.z; sA1[r * 65 + col4 + 3] = v1.w;
        sA2[r * 65 + col4 + 0] = v2.x; sA2[r * 65 + col4 + 1] = v2.y;
        sA2[r * 65 + col4 + 2] = v2.z; sA2[r * 65 + col4 + 3] = v2.w;
    }
    __syncthreads();

    int tj = tid & 15;
    int ti = tid >> 4;
    float acc[4][4] = {};
    const float4* W1f = (const float4*)sW1;
    const float4* W2f = (const float4*)sW2;
#pragma unroll 8
    for (int k = 0; k < 64; k++) {
        float4 w1 = W1f[k * 16 + tj];
        float4 w2 = W2f[k * 16 + tj];
#pragma unroll
        for (int d = 0; d < 4; d++) {
            float a1 = sA1[(ti * 4 + d) * 65 + k];
            float a2 = sA2[(ti * 4 + d) * 65 + k];
            acc[d][0] += a1 * w1.x; acc[d][0] += a2 * w2.x;
            acc[d][1] += a1 * w1.y; acc[d][1] += a2 * w2.y;
            acc[d][2] += a1 * w1.z; acc[d][2] += a2 * w2.z;
            acc[d][3] += a1 * w1.w; acc[d][3] += a2 * w2.w;
        }
    }

    if (!FUSE_HEAD) {
#pragma unroll
        for (int d = 0; d < 4; d++) {
            int g = i0 + ti * 4 + d;
            if (g < NN) {
                float4 o;
                o.x = fmaxf(acc[d][0] + sB[tj * 4 + 0], 0.f);
                o.y = fmaxf(acc[d][1] + sB[tj * 4 + 1], 0.f);
                o.z = fmaxf(acc[d][2] + sB[tj * 4 + 2], 0.f);
                o.w = fmaxf(acc[d][3] + sB[tj * 4 + 3], 0.f);
                *(float4*)&out[(size_t)g * 64 + tj * 4] = o;
                __hip_bfloat16 ba = __float2bfloat16(o.x), bb = __float2bfloat16(o.y),
                               bc = __float2bfloat16(o.z), bd = __float2bfloat16(o.w);
                ushort4 u;
                u.x = *(unsigned short*)&ba; u.y = *(unsigned short*)&bb;
                u.z = *(unsigned short*)&bc; u.w = *(unsigned short*)&bd;
                out_bf16[((size_t)g * 64 + tj * 4) >> 2] = u;
            }
        }
    } else {
#pragma unroll
        for (int d = 0; d < 4; d++) {
            float psum = 0.f;
            psum += fmaxf(acc[d][0] + sB[tj * 4 + 0], 0.f) * sWfc[tj * 4 + 0];
            psum += fmaxf(acc[d][1] + sB[tj * 4 + 1], 0.f) * sWfc[tj * 4 + 1];
            psum += fmaxf(acc[d][2] + sB[tj * 4 + 2], 0.f) * sWfc[tj * 4 + 2];
            psum += fmaxf(acc[d][3] + sB[tj * 4 + 3], 0.f) * sWfc[tj * 4 + 3];
            sRed[(ti * 4 + d) * 17 + tj] = psum;
        }
        __syncthreads();
        if (tid < 64) {
            float sum = bfc[0];
#pragma unroll
            for (int c = 0; c < 16; c++) sum += sRed[tid * 17 + c];
            int g = i0 + tid;
            if (g < NN) out[g] = sum;
        }
    }
}

extern "C" void kernel_launch(void* const* d_in, const int* in_sizes, int n_in,
                              void* d_out, int out_size, void* d_ws, size_t ws_size,
                              hipStream_t stream) {
    const float* x   = (const float*)d_in[0];
    const int*   ei  = (const int*)d_in[1];
    const float* Wl1 = (const float*)d_in[2];
    const float* bl1 = (const float*)d_in[3];
    const float* Wr1 = (const float*)d_in[4];
    const float* Wl2 = (const float*)d_in[5];
    const float* bl2 = (const float*)d_in[6];
    const float* Wr2 = (const float*)d_in[7];
    const float* Wfc = (const float*)d_in[8];
    const float* bfc = (const float*)d_in[9];
    float* out = (float*)d_out;

    const int* src = ei;       // edge_index[0]
    const int* dst = ei + NE;  // edge_index[1]

    char* p = (char*)d_ws;
    auto carve = [&](size_t bytes) {
        char* q = p;
        p += (bytes + 255) & ~size_t(255);
        return q;
    };
    int*            offsets = (int*)carve((size_t)(NN + 1) * 4);
    float*          inv_deg = (float*)carve((size_t)NN * 4);
    int*            ssrc    = (int*)carve((size_t)NE * 4);
    unsigned short* xb      = (unsigned short*)carve((size_t)NN * 64 * 2);
    unsigned short* h1b     = (unsigned short*)carve((size_t)NN * 64 * 2);
    float*          h1      = (float*)carve((size_t)NN * 64 * 4);
    float*          agg     = (float*)carve((size_t)NN * 64 * 4);
    // temporaries alias onto agg (dead before k_aggregate first writes agg):
    int2* pairs        = (int2*)agg;
    int*  hist         = (int*)(pairs + NE);
    int*  bin_total    = hist + (size_t)NBUCK * P1B;
    int*  bucket_start = bin_total + NBUCK;  // NBUCK+1 ints

    const int n4   = NN * 64 / 4;
    const int tile = (NN + 63) / 64;  // 1563

    k_to_bf16<<<(n4 + 255) / 256, 256, 0, stream>>>((const float4*)x, (ushort4*)xb, n4);

    // graph build: two-level LDS counting sort, zero global atomics
    k_p1_hist<<<P1B, 256, 0, stream>>>(dst, hist);
    k_bin_total<<<NBUCK, 256, 0, stream>>>(hist, bin_total);
    k_bin_base<<<1, 512, 0, stream>>>(bin_total, bucket_start, offsets);
    k_cursor_base<<<NBUCK, 512, 0, stream>>>(hist, bucket_start);
    k_p1_scatter<<<P1B, 256, 0, stream>>>(src, dst, hist, pairs);
    k_bucket_csr<<<NBUCK, 256, 0, stream>>>(pairs, bucket_start, ssrc, offsets, inv_deg);

    // layer 1: gather bf16 x -> agg (fp32), then dual GEMM (writes h1 fp32 + h1b bf16)
    k_aggregate<<<(NN + 3) / 4, 256, 0, stream>>>((const uint4*)xb, ssrc, offsets, inv_deg, agg);
    k_linear<false><<<tile, 256, 0, stream>>>(agg, x, Wl1, Wr1, bl1, Wfc, bfc, h1, (ushort4*)h1b);
    // layer 2 + fused head
    k_aggregate<<<(NN + 3) / 4, 256, 0, stream>>>((const uint4*)h1b, ssrc, offsets, inv_deg, agg);
    k_linear<true><<<tile, 256, 0, stream>>>(agg, h1, Wl2, Wr2, bl2, Wfc, bfc, out, nullptr);
}

// Round 9
// 288.292 us; speedup vs baseline: 1.5572x; 1.0305x over previous
//
#include <hip/hip_runtime.h>
#include <hip/hip_fp16.h>

#define NN 100000
#define NE 1600000
#define SHIFT 8
#define NBUCK 391   // ceil(NN / 256) dst-buckets, 256 nodes each
#define P1B   391   // pass-1 blocks
#define EPB   4093  // ceil(NE / P1B) edges per pass-1 block

typedef _Float16 f16x8 __attribute__((ext_vector_type(8)));
union H8U4 { f16x8 h; uint4 u; };

// ---------------- fp32 -> f16 copy (for gather operand) ----------------
__global__ __launch_bounds__(256) void k_to_f16(const float4* __restrict__ in, ushort4* __restrict__ out, int n4) {
    int i = blockIdx.x * 256 + threadIdx.x;
    if (i < n4) {
        float4 f = in[i];
        _Float16 a = (_Float16)f.x, b = (_Float16)f.y, c = (_Float16)f.z, d = (_Float16)f.w;
        ushort4 u;
        u.x = *(unsigned short*)&a; u.y = *(unsigned short*)&b;
        u.z = *(unsigned short*)&c; u.w = *(unsigned short*)&d;
        out[i] = u;
    }
}

// ---------------- pass 1a: per-block LDS histogram over dst buckets ----------------
__global__ __launch_bounds__(256) void k_p1_hist(const int* __restrict__ dst, int* __restrict__ hist) {
    __shared__ int h[NBUCK];
    int t = threadIdx.x, blk = blockIdx.x;
    for (int i = t; i < NBUCK; i += 256) h[i] = 0;
    __syncthreads();
    int beg = blk * EPB, end = min(beg + EPB, NE);
    for (int e = beg + t; e < end; e += 256) atomicAdd(&h[dst[e] >> SHIFT], 1);
    __syncthreads();
    for (int i = t; i < NBUCK; i += 256) hist[(size_t)i * P1B + blk] = h[i];
}

// ---------------- pass 1b: bucket totals ----------------
__global__ __launch_bounds__(256) void k_bin_total(const int* __restrict__ hist, int* __restrict__ bin_total) {
    __shared__ int sd[256];
    int b = blockIdx.x, t = threadIdx.x;
    int v = 0;
    for (int i = t; i < P1B; i += 256) v += hist[(size_t)b * P1B + i];
    sd[t] = v;
    __syncthreads();
    for (int s = 128; s > 0; s >>= 1) {
        if (t < s) sd[t] += sd[t + s];
        __syncthreads();
    }
    if (t == 0) bin_total[b] = sd[0];
}

// ---------------- pass 1c: exclusive scan of bucket totals -> bucket_start ----------------
__global__ __launch_bounds__(512) void k_bin_base(const int* __restrict__ bin_total, int* __restrict__ bucket_start,
                                                  int* __restrict__ offsets) {
    __shared__ int s[512];
    int t = threadIdx.x;
    int v = (t < NBUCK) ? bin_total[t] : 0;
    s[t] = v;
    __syncthreads();
    for (int off = 1; off < 512; off <<= 1) {
        int add = (t >= off) ? s[t - off] : 0;
        __syncthreads();
        s[t] += add;
        __syncthreads();
    }
    if (t < NBUCK) bucket_start[t] = s[t] - v;
    if (t == 0) { bucket_start[NBUCK] = NE; offsets[NN] = NE; }
}

// ---------------- pass 1d: per-bucket scan over blocks -> cursor bases (in-place on hist) ----------------
__global__ __launch_bounds__(512) void k_cursor_base(int* __restrict__ hist, const int* __restrict__ bucket_start) {
    __shared__ int s[512];
    int b = blockIdx.x, t = threadIdx.x;
    int v = (t < P1B) ? hist[(size_t)b * P1B + t] : 0;
    s[t] = v;
    __syncthreads();
    for (int off = 1; off < 512; off <<= 1) {
        int add = (t >= off) ? s[t - off] : 0;
        __syncthreads();
        s[t] += add;
        __syncthreads();
    }
    if (t < P1B) hist[(size_t)b * P1B + t] = bucket_start[b] + s[t] - v;
}

// ---------------- pass 1e: scatter packed (src | (dst&255)<<17) into bucket order ----------------
__global__ __launch_bounds__(256) void k_p1_scatter(const int* __restrict__ src, const int* __restrict__ dst,
                                                    const int* __restrict__ hist, unsigned int* __restrict__ pairs) {
    __shared__ int cur[NBUCK];
    int t = threadIdx.x, blk = blockIdx.x;
    for (int i = t; i < NBUCK; i += 256) cur[i] = hist[(size_t)i * P1B + blk];
    __syncthreads();
    int beg = blk * EPB, end = min(beg + EPB, NE);
    for (int e = beg + t; e < end; e += 256) {
        int d = dst[e];
        int pos = atomicAdd(&cur[d >> SHIFT], 1);
        pairs[pos] = (unsigned int)src[e] | ((unsigned int)(d & 255) << 17);
    }
}

// ---------------- pass 2: per-bucket CSR finalize (LDS count + scan + scatter) ----------------
__global__ __launch_bounds__(256) void k_bucket_csr(const unsigned int* __restrict__ pairs,
                                                    const int* __restrict__ bucket_start,
                                                    int* __restrict__ ssrc, int* __restrict__ offsets,
                                                    float* __restrict__ inv_deg) {
    __shared__ int cnt[256];
    __shared__ int excl[256];
    int b = blockIdx.x, t = threadIdx.x;
    cnt[t] = 0;
    __syncthreads();
    int beg = bucket_start[b], end = bucket_start[b + 1];
    for (int e = beg + t; e < end; e += 256) atomicAdd(&cnt[pairs[e] >> 17], 1);
    __syncthreads();
    int deg = cnt[t];
    excl[t] = deg;
    __syncthreads();
    for (int off = 1; off < 256; off <<= 1) {
        int add = (t >= off) ? excl[t - off] : 0;
        __syncthreads();
        excl[t] += add;
        __syncthreads();
    }
    int ex = excl[t] - deg;
    int node = (b << SHIFT) + t;
    if (node < NN) {
        offsets[node] = beg + ex;
        inv_deg[node] = (deg > 0) ? (1.0f / (float)deg) : 0.0f;
    }
    __syncthreads();
    cnt[t] = beg + ex;  // cursor
    __syncthreads();
    for (int e = beg + t; e < end; e += 256) {
        unsigned int pr = pairs[e];
        int pos = atomicAdd(&cnt[pr >> 17], 1);
        ssrc[pos] = (int)(pr & 0x1FFFFu);
    }
}

// ---------------- mean aggregation: one wave per node, 8 edges per wave-request ----------------
// Lane l: chunk c=l&7 (features 8c..8c+7 as uint4 of f16x8), edge-slot g=l>>3.
// Accumulate in packed f16 (v_pk_add_f16): 4 VALU per edge-slot.
__global__ __launch_bounds__(256) void k_aggregate(const uint4* __restrict__ featq,
                                                   const int* __restrict__ ssrc,
                                                   const int* __restrict__ offsets, const float* __restrict__ inv_deg,
                                                   float* __restrict__ out) {
    int node = blockIdx.x * 4 + (threadIdx.x >> 6);
    int lane = threadIdx.x & 63;
    if (node >= NN) return;
    int c = lane & 7, g = lane >> 3;
    int beg = offsets[node], end = offsets[node + 1];
    H8U4 acc;
    acc.h = (f16x8)(_Float16)0;
    int e = beg;

    for (; e + 16 <= end; e += 16) {
        int i0 = ssrc[e + g];
        int i1 = ssrc[e + 8 + g];
        H8U4 q0, q1;
        q0.u = featq[(size_t)i0 * 8 + c];
        q1.u = featq[(size_t)i1 * 8 + c];
        acc.h += q0.h;
        acc.h += q1.h;
    }
    for (; e < end; e += 8) {
        int m = end - e;  // 1..8 valid edges
        int idx = ssrc[e + (g < m ? g : m - 1)];
        H8U4 q;
        q.u = featq[(size_t)idx * 8 + c];
        if (g < m) acc.h += q.h;
    }

    // fold the 8 edge-slots together (lanes differing in bits 3..5)
#pragma unroll
    for (int mask = 8; mask <= 32; mask <<= 1) {
        H8U4 o;
        o.u.x = __shfl_xor(acc.u.x, mask);
        o.u.y = __shfl_xor(acc.u.y, mask);
        o.u.z = __shfl_xor(acc.u.z, mask);
        o.u.w = __shfl_xor(acc.u.w, mask);
        acc.h += o.h;
    }

    if (g == 0) {
        float s = inv_deg[node];
        float4 o0 = {(float)acc.h[0] * s, (float)acc.h[1] * s, (float)acc.h[2] * s, (float)acc.h[3] * s};
        float4 o1 = {(float)acc.h[4] * s, (float)acc.h[5] * s, (float)acc.h[6] * s, (float)acc.h[7] * s};
        *(float4*)&out[(size_t)node * 64 + c * 8]     = o0;
        *(float4*)&out[(size_t)node * 64 + c * 8 + 4] = o1;
    }
}

// ---------------- fused dual GEMM: out = relu(A1@W1 + b + A2@W2), optional @Wfc+bfc head ----------------
template <bool FUSE_HEAD>
__global__ __launch_bounds__(256) void k_linear(const float* __restrict__ A1, const float* __restrict__ A2,
                                                const float* __restrict__ W1, const float* __restrict__ W2,
                                                const float* __restrict__ bias,
                                                const float* __restrict__ Wfc, const float* __restrict__ bfc,
                                                float* __restrict__ out, ushort4* __restrict__ out_f16) {
    __shared__ __align__(16) float sA1[64 * 65];
    __shared__ __align__(16) float sA2[64 * 65];
    __shared__ __align__(16) float sW1[64 * 64];
    __shared__ __align__(16) float sW2[64 * 64];
    __shared__ float sB[64];
    __shared__ float sWfc[64];
    __shared__ float sRed[64 * 17];

    int tid = threadIdx.x;
    int i0 = blockIdx.x * 64;

#pragma unroll
    for (int r = 0; r < 4; r++) {
        int idx = r * 1024 + tid * 4;
        *(float4*)&sW1[idx] = *(const float4*)&W1[idx];
        *(float4*)&sW2[idx] = *(const float4*)&W2[idx];
    }
    if (tid < 64) {
        sB[tid] = bias[tid];
        sWfc[tid] = FUSE_HEAD ? Wfc[tid] : 0.f;
    }

    int col4 = (tid & 15) * 4;
#pragma unroll
    for (int rep = 0; rep < 4; rep++) {
        int r = rep * 16 + (tid >> 4);
        int g = i0 + r;
        float4 v1 = {0, 0, 0, 0}, v2 = {0, 0, 0, 0};
        if (g < NN) {
            v1 = *(const float4*)&A1[(size_t)g * 64 + col4];
            v2 = *(const float4*)&A2[(size_t)g * 64 + col4];
        }
        sA1[r * 65 + col4 + 0] = v1.x; sA1[r * 65 + col4 + 1] = v1.y;
        sA1[r * 65 + col4 + 2] = v1.z; sA1[r * 65 + col4 + 3] = v1.w;
        sA2[r * 65 + col4 + 0] = v2.x; sA2[r * 65 + col4 + 1] = v2.y;
        sA2[r * 65 + col4 + 2] = v2.z; sA2[r * 65 + col4 + 3] = v2.w;
    }
    __syncthreads();

    int tj = tid & 15;
    int ti = tid >> 4;
    float acc[4][4] = {};
    const float4* W1f = (const float4*)sW1;
    const float4* W2f = (const float4*)sW2;
#pragma unroll 8
    for (int k = 0; k < 64; k++) {
        float4 w1 = W1f[k * 16 + tj];
        float4 w2 = W2f[k * 16 + tj];
#pragma unroll
        for (int d = 0; d < 4; d++) {
            float a1 = sA1[(ti * 4 + d) * 65 + k];
            float a2 = sA2[(ti * 4 + d) * 65 + k];
            acc[d][0] += a1 * w1.x; acc[d][0] += a2 * w2.x;
            acc[d][1] += a1 * w1.y; acc[d][1] += a2 * w2.y;
            acc[d][2] += a1 * w1.z; acc[d][2] += a2 * w2.z;
            acc[d][3] += a1 * w1.w; acc[d][3] += a2 * w2.w;
        }
    }

    if (!FUSE_HEAD) {
#pragma unroll
        for (int d = 0; d < 4; d++) {
            int g = i0 + ti * 4 + d;
            if (g < NN) {
                float4 o;
                o.x = fmaxf(acc[d][0] + sB[tj * 4 + 0], 0.f);
                o.y = fmaxf(acc[d][1] + sB[tj * 4 + 1], 0.f);
                o.z = fmaxf(acc[d][2] + sB[tj * 4 + 2], 0.f);
                o.w = fmaxf(acc[d][3] + sB[tj * 4 + 3], 0.f);
                *(float4*)&out[(size_t)g * 64 + tj * 4] = o;
                _Float16 ha = (_Float16)o.x, hb = (_Float16)o.y, hc = (_Float16)o.z, hd = (_Float16)o.w;
                ushort4 u;
                u.x = *(unsigned short*)&ha; u.y = *(unsigned short*)&hb;
                u.z = *(unsigned short*)&hc; u.w = *(unsigned short*)&hd;
                out_f16[((size_t)g * 64 + tj * 4) >> 2] = u;
            }
        }
    } else {
#pragma unroll
        for (int d = 0; d < 4; d++) {
            float psum = 0.f;
            psum += fmaxf(acc[d][0] + sB[tj * 4 + 0], 0.f) * sWfc[tj * 4 + 0];
            psum += fmaxf(acc[d][1] + sB[tj * 4 + 1], 0.f) * sWfc[tj * 4 + 1];
            psum += fmaxf(acc[d][2] + sB[tj * 4 + 2], 0.f) * sWfc[tj * 4 + 2];
            psum += fmaxf(acc[d][3] + sB[tj * 4 + 3], 0.f) * sWfc[tj * 4 + 3];
            sRed[(ti * 4 + d) * 17 + tj] = psum;
        }
        __syncthreads();
        if (tid < 64) {
            float sum = bfc[0];
#pragma unroll
            for (int c = 0; c < 16; c++) sum += sRed[tid * 17 + c];
            int g = i0 + tid;
            if (g < NN) out[g] = sum;
        }
    }
}

extern "C" void kernel_launch(void* const* d_in, const int* in_sizes, int n_in,
                              void* d_out, int out_size, void* d_ws, size_t ws_size,
                              hipStream_t stream) {
    const float* x   = (const float*)d_in[0];
    const int*   ei  = (const int*)d_in[1];
    const float* Wl1 = (const float*)d_in[2];
    const float* bl1 = (const float*)d_in[3];
    const float* Wr1 = (const float*)d_in[4];
    const float* Wl2 = (const float*)d_in[5];
    const float* bl2 = (const float*)d_in[6];
    const float* Wr2 = (const float*)d_in[7];
    const float* Wfc = (const float*)d_in[8];
    const float* bfc = (const float*)d_in[9];
    float* out = (float*)d_out;

    const int* src = ei;       // edge_index[0]
    const int* dst = ei + NE;  // edge_index[1]

    char* p = (char*)d_ws;
    auto carve = [&](size_t bytes) {
        char* q = p;
        p += (bytes + 255) & ~size_t(255);
        return q;
    };
    int*            offsets = (int*)carve((size_t)(NN + 1) * 4);
    float*          inv_deg = (float*)carve((size_t)NN * 4);
    int*            ssrc    = (int*)carve((size_t)NE * 4);
    unsigned short* xh      = (unsigned short*)carve((size_t)NN * 64 * 2);
    unsigned short* h1h     = (unsigned short*)carve((size_t)NN * 64 * 2);
    float*          h1      = (float*)carve((size_t)NN * 64 * 4);
    float*          agg     = (float*)carve((size_t)NN * 64 * 4);
    // temporaries alias onto agg (dead before k_aggregate first writes agg):
    unsigned int* pairs        = (unsigned int*)agg;              // 6.4 MB
    int*          hist         = (int*)(pairs + NE);              // 611 KB
    int*          bin_total    = hist + (size_t)NBUCK * P1B;
    int*          bucket_start = bin_total + NBUCK;               // NBUCK+1 ints

    const int n4   = NN * 64 / 4;
    const int tile = (NN + 63) / 64;  // 1563

    k_to_f16<<<(n4 + 255) / 256, 256, 0, stream>>>((const float4*)x, (ushort4*)xh, n4);

    // graph build: two-level LDS counting sort, zero global atomics
    k_p1_hist<<<P1B, 256, 0, stream>>>(dst, hist);
    k_bin_total<<<NBUCK, 256, 0, stream>>>(hist, bin_total);
    k_bin_base<<<1, 512, 0, stream>>>(bin_total, bucket_start, offsets);
    k_cursor_base<<<NBUCK, 512, 0, stream>>>(hist, bucket_start);
    k_p1_scatter<<<P1B, 256, 0, stream>>>(src, dst, hist, pairs);
    k_bucket_csr<<<NBUCK, 256, 0, stream>>>(pairs, bucket_start, ssrc, offsets, inv_deg);

    // layer 1: gather f16 x -> agg (fp32), then dual GEMM (writes h1 fp32 + h1h f16)
    k_aggregate<<<(NN + 3) / 4, 256, 0, stream>>>((const uint4*)xh, ssrc, offsets, inv_deg, agg);
    k_linear<false><<<tile, 256, 0, stream>>>(agg, x, Wl1, Wr1, bl1, Wfc, bfc, h1, (ushort4*)h1h);
    // layer 2 + fused head
    k_aggregate<<<(NN + 3) / 4, 256, 0, stream>>>((const uint4*)h1h, ssrc, offsets, inv_deg, agg);
    k_linear<true><<<tile, 256, 0, stream>>>(agg, h1, Wl2, Wr2, bl2, Wfc, bfc, out, nullptr);
}

// Round 10
// 260.377 us; speedup vs baseline: 1.7241x; 1.1072x over previous
//
#include <hip/hip_runtime.h>
#include <hip/hip_fp16.h>

#define NN 100000
#define NE 1600000
#define SHIFT 8
#define NBUCK 391   // ceil(NN / 256) dst-buckets, 256 nodes each
#define P1B   391   // pass-1 blocks
#define EPB   4093  // ceil(NE / P1B) edges per pass-1 block

typedef _Float16 f16x8 __attribute__((ext_vector_type(8)));
typedef float f32x4 __attribute__((ext_vector_type(4)));
union H8U4 { f16x8 h; uint4 u; };

// ---------------- fp32 -> f16 copy (for gather operand) ----------------
__global__ __launch_bounds__(256) void k_to_f16(const float4* __restrict__ in, ushort4* __restrict__ out, int n4) {
    int i = blockIdx.x * 256 + threadIdx.x;
    if (i < n4) {
        float4 f = in[i];
        _Float16 a = (_Float16)f.x, b = (_Float16)f.y, c = (_Float16)f.z, d = (_Float16)f.w;
        ushort4 u;
        u.x = *(unsigned short*)&a; u.y = *(unsigned short*)&b;
        u.z = *(unsigned short*)&c; u.w = *(unsigned short*)&d;
        out[i] = u;
    }
}

// ---------------- weight prep: WcatT[n][k] f16, k<64 -> Wl[k][n], k>=64 -> Wr[k-64][n] ----------------
__global__ __launch_bounds__(256) void k_prep_w(const float* __restrict__ Wl, const float* __restrict__ Wr,
                                                unsigned short* __restrict__ wt) {
    int idx = blockIdx.x * 256 + threadIdx.x;  // 64*128 = 8192
    if (idx < 64 * 128) {
        int n = idx >> 7, k = idx & 127;
        float v = (k < 64) ? Wl[k * 64 + n] : Wr[(k - 64) * 64 + n];
        _Float16 h = (_Float16)v;
        wt[idx] = *(unsigned short*)&h;
    }
}

// ---------------- pass 1a: per-block LDS histogram over dst buckets ----------------
__global__ __launch_bounds__(256) void k_p1_hist(const int* __restrict__ dst, int* __restrict__ hist) {
    __shared__ int h[NBUCK];
    int t = threadIdx.x, blk = blockIdx.x;
    for (int i = t; i < NBUCK; i += 256) h[i] = 0;
    __syncthreads();
    int beg = blk * EPB, end = min(beg + EPB, NE);
    for (int e = beg + t; e < end; e += 256) atomicAdd(&h[dst[e] >> SHIFT], 1);
    __syncthreads();
    for (int i = t; i < NBUCK; i += 256) hist[(size_t)i * P1B + blk] = h[i];
}

// ---------------- pass 1b: bucket totals ----------------
__global__ __launch_bounds__(256) void k_bin_total(const int* __restrict__ hist, int* __restrict__ bin_total) {
    __shared__ int sd[256];
    int b = blockIdx.x, t = threadIdx.x;
    int v = 0;
    for (int i = t; i < P1B; i += 256) v += hist[(size_t)b * P1B + i];
    sd[t] = v;
    __syncthreads();
    for (int s = 128; s > 0; s >>= 1) {
        if (t < s) sd[t] += sd[t + s];
        __syncthreads();
    }
    if (t == 0) bin_total[b] = sd[0];
}

// ---------------- pass 1c: exclusive scan of bucket totals -> bucket_start ----------------
__global__ __launch_bounds__(512) void k_bin_base(const int* __restrict__ bin_total, int* __restrict__ bucket_start,
                                                  int* __restrict__ offsets) {
    __shared__ int s[512];
    int t = threadIdx.x;
    int v = (t < NBUCK) ? bin_total[t] : 0;
    s[t] = v;
    __syncthreads();
    for (int off = 1; off < 512; off <<= 1) {
        int add = (t >= off) ? s[t - off] : 0;
        __syncthreads();
        s[t] += add;
        __syncthreads();
    }
    if (t < NBUCK) bucket_start[t] = s[t] - v;
    if (t == 0) { bucket_start[NBUCK] = NE; offsets[NN] = NE; }
}

// ---------------- pass 1d: per-bucket scan over blocks -> cursor bases (in-place on hist) ----------------
__global__ __launch_bounds__(512) void k_cursor_base(int* __restrict__ hist, const int* __restrict__ bucket_start) {
    __shared__ int s[512];
    int b = blockIdx.x, t = threadIdx.x;
    int v = (t < P1B) ? hist[(size_t)b * P1B + t] : 0;
    s[t] = v;
    __syncthreads();
    for (int off = 1; off < 512; off <<= 1) {
        int add = (t >= off) ? s[t - off] : 0;
        __syncthreads();
        s[t] += add;
        __syncthreads();
    }
    if (t < P1B) hist[(size_t)b * P1B + t] = bucket_start[b] + s[t] - v;
}

// ---------------- pass 1e: scatter packed (src | (dst&255)<<17) into bucket order ----------------
__global__ __launch_bounds__(256) void k_p1_scatter(const int* __restrict__ src, const int* __restrict__ dst,
                                                    const int* __restrict__ hist, unsigned int* __restrict__ pairs) {
    __shared__ int cur[NBUCK];
    int t = threadIdx.x, blk = blockIdx.x;
    for (int i = t; i < NBUCK; i += 256) cur[i] = hist[(size_t)i * P1B + blk];
    __syncthreads();
    int beg = blk * EPB, end = min(beg + EPB, NE);
    for (int e = beg + t; e < end; e += 256) {
        int d = dst[e];
        int pos = atomicAdd(&cur[d >> SHIFT], 1);
        pairs[pos] = (unsigned int)src[e] | ((unsigned int)(d & 255) << 17);
    }
}

// ---------------- pass 2: per-bucket CSR finalize (LDS count + scan + scatter) ----------------
__global__ __launch_bounds__(256) void k_bucket_csr(const unsigned int* __restrict__ pairs,
                                                    const int* __restrict__ bucket_start,
                                                    int* __restrict__ ssrc, int* __restrict__ offsets,
                                                    float* __restrict__ inv_deg) {
    __shared__ int cnt[256];
    __shared__ int excl[256];
    int b = blockIdx.x, t = threadIdx.x;
    cnt[t] = 0;
    __syncthreads();
    int beg = bucket_start[b], end = bucket_start[b + 1];
    for (int e = beg + t; e < end; e += 256) atomicAdd(&cnt[pairs[e] >> 17], 1);
    __syncthreads();
    int deg = cnt[t];
    excl[t] = deg;
    __syncthreads();
    for (int off = 1; off < 256; off <<= 1) {
        int add = (t >= off) ? excl[t - off] : 0;
        __syncthreads();
        excl[t] += add;
        __syncthreads();
    }
    int ex = excl[t] - deg;
    int node = (b << SHIFT) + t;
    if (node < NN) {
        offsets[node] = beg + ex;
        inv_deg[node] = (deg > 0) ? (1.0f / (float)deg) : 0.0f;
    }
    __syncthreads();
    cnt[t] = beg + ex;  // cursor
    __syncthreads();
    for (int e = beg + t; e < end; e += 256) {
        unsigned int pr = pairs[e];
        int pos = atomicAdd(&cnt[pr >> 17], 1);
        ssrc[pos] = (int)(pr & 0x1FFFFu);
    }
}

// ---------------- mean aggregation: one wave per node, 8 edges per wave-request, f16 in/out ----------------
__global__ __launch_bounds__(256) void k_aggregate(const uint4* __restrict__ featq,
                                                   const int* __restrict__ ssrc,
                                                   const int* __restrict__ offsets, const float* __restrict__ inv_deg,
                                                   uint4* __restrict__ outq) {
    int node = blockIdx.x * 4 + (threadIdx.x >> 6);
    int lane = threadIdx.x & 63;
    if (node >= NN) return;
    int c = lane & 7, g = lane >> 3;
    int beg = offsets[node], end = offsets[node + 1];
    H8U4 acc;
    acc.h = (f16x8)(_Float16)0;
    int e = beg;

    for (; e + 16 <= end; e += 16) {
        int i0 = ssrc[e + g];
        int i1 = ssrc[e + 8 + g];
        H8U4 q0, q1;
        q0.u = featq[(size_t)i0 * 8 + c];
        q1.u = featq[(size_t)i1 * 8 + c];
        acc.h += q0.h;
        acc.h += q1.h;
    }
    for (; e < end; e += 8) {
        int m = end - e;  // 1..8 valid edges
        int idx = ssrc[e + (g < m ? g : m - 1)];
        H8U4 q;
        q.u = featq[(size_t)idx * 8 + c];
        if (g < m) acc.h += q.h;
    }

#pragma unroll
    for (int mask = 8; mask <= 32; mask <<= 1) {
        H8U4 o;
        o.u.x = __shfl_xor(acc.u.x, mask);
        o.u.y = __shfl_xor(acc.u.y, mask);
        o.u.z = __shfl_xor(acc.u.z, mask);
        o.u.w = __shfl_xor(acc.u.w, mask);
        acc.h += o.h;
    }

    if (g == 0) {
        float s = inv_deg[node];
        H8U4 r;
#pragma unroll
        for (int j = 0; j < 8; j++) r.h[j] = (_Float16)((float)acc.h[j] * s);
        outq[(size_t)node * 8 + c] = r.u;
    }
}

// ---------------- MFMA dual GEMM: relu([agg|root] @ WcatT^T + b), optional @Wfc+bfc head ----------------
// Block 256 = 4 waves; wave handles 16 nodes x 64 outputs = 16x mfma_f32_16x16x32_f16 over K=128.
// Fragments (verified m92/m97 gemm_bt pattern): A row-major [m][k], B^T row-major [n][k],
// C/D: col=lane&15, row=quad*4+reg. Zero LDS.
template <bool FUSE_HEAD>
__global__ __launch_bounds__(256) void k_linear(const uint4* __restrict__ aggq, const uint4* __restrict__ rootq,
                                                const uint4* __restrict__ wtq,   // WcatT f16 [64][128] as uint4
                                                const float* __restrict__ bias,
                                                const float* __restrict__ Wfc, const float* __restrict__ bfc,
                                                float* __restrict__ out_f32, unsigned short* __restrict__ out_f16) {
    int tid = threadIdx.x;
    int wave = tid >> 6, lane = tid & 63;
    int nb = blockIdx.x * 64 + wave * 16;
    int m = lane & 15, quad = lane >> 4;

    int an = nb + m;
    if (an > NN - 1) an = NN - 1;
    H8U4 a[4];
    a[0].u = aggq[(size_t)an * 8 + quad];
    a[1].u = aggq[(size_t)an * 8 + 4 + quad];
    a[2].u = rootq[(size_t)an * 8 + quad];
    a[3].u = rootq[(size_t)an * 8 + 4 + quad];

    f32x4 acc[4];
#pragma unroll
    for (int n = 0; n < 4; n++) acc[n] = (f32x4){0.f, 0.f, 0.f, 0.f};

#pragma unroll
    for (int ncol = 0; ncol < 4; ncol++) {
        int col = ncol * 16 + m;
#pragma unroll
        for (int ki = 0; ki < 4; ki++) {
            H8U4 b;
            b.u = wtq[col * 16 + ki * 4 + quad];
            acc[ncol] = __builtin_amdgcn_mfma_f32_16x16x32_f16(a[ki].h, b.h, acc[ncol], 0, 0, 0);
        }
    }

    float bs[4];
#pragma unroll
    for (int ncol = 0; ncol < 4; ncol++) bs[ncol] = bias[ncol * 16 + m];

    if (!FUSE_HEAD) {
#pragma unroll
        for (int r = 0; r < 4; r++) {
            int node = nb + quad * 4 + r;
            if (node < NN) {
#pragma unroll
                for (int ncol = 0; ncol < 4; ncol++) {
                    float v = fmaxf(acc[ncol][r] + bs[ncol], 0.f);
                    _Float16 hv = (_Float16)v;
                    out_f16[(size_t)node * 64 + ncol * 16 + m] = *(unsigned short*)&hv;
                }
            }
        }
    } else {
        float wf[4];
#pragma unroll
        for (int ncol = 0; ncol < 4; ncol++) wf[ncol] = Wfc[ncol * 16 + m];
#pragma unroll
        for (int r = 0; r < 4; r++) {
            int node = nb + quad * 4 + r;
            float partial = 0.f;
#pragma unroll
            for (int ncol = 0; ncol < 4; ncol++)
                partial += fmaxf(acc[ncol][r] + bs[ncol], 0.f) * wf[ncol];
            partial += __shfl_xor(partial, 1);
            partial += __shfl_xor(partial, 2);
            partial += __shfl_xor(partial, 4);
            partial += __shfl_xor(partial, 8);
            if (m == 0 && node < NN) out_f32[node] = partial + bfc[0];
        }
    }
}

extern "C" void kernel_launch(void* const* d_in, const int* in_sizes, int n_in,
                              void* d_out, int out_size, void* d_ws, size_t ws_size,
                              hipStream_t stream) {
    const float* x   = (const float*)d_in[0];
    const int*   ei  = (const int*)d_in[1];
    const float* Wl1 = (const float*)d_in[2];
    const float* bl1 = (const float*)d_in[3];
    const float* Wr1 = (const float*)d_in[4];
    const float* Wl2 = (const float*)d_in[5];
    const float* bl2 = (const float*)d_in[6];
    const float* Wr2 = (const float*)d_in[7];
    const float* Wfc = (const float*)d_in[8];
    const float* bfc = (const float*)d_in[9];
    float* out = (float*)d_out;

    const int* src = ei;       // edge_index[0]
    const int* dst = ei + NE;  // edge_index[1]

    char* p = (char*)d_ws;
    auto carve = [&](size_t bytes) {
        char* q = p;
        p += (bytes + 255) & ~size_t(255);
        return q;
    };
    int*            offsets = (int*)carve((size_t)(NN + 1) * 4);
    float*          inv_deg = (float*)carve((size_t)NN * 4);
    int*            ssrc    = (int*)carve((size_t)NE * 4);
    unsigned short* xh      = (unsigned short*)carve((size_t)NN * 64 * 2);
    unsigned short* h1h     = (unsigned short*)carve((size_t)NN * 64 * 2);
    unsigned short* aggh    = (unsigned short*)carve((size_t)NN * 64 * 2);
    unsigned short* wt1     = (unsigned short*)carve(64 * 128 * 2);
    unsigned short* wt2     = (unsigned short*)carve(64 * 128 * 2);
    // graph-build temporaries alias onto aggh (dead before k_aggregate first writes aggh):
    unsigned int* pairs        = (unsigned int*)aggh;             // 6.4 MB (aggh is 12.8 MB)
    int*          hist         = (int*)(pairs + NE);              // 611 KB
    int*          bin_total    = hist + (size_t)NBUCK * P1B;
    int*          bucket_start = bin_total + NBUCK;               // NBUCK+1 ints

    const int n4   = NN * 64 / 4;
    const int tile = (NN + 63) / 64;  // 1563

    k_to_f16<<<(n4 + 255) / 256, 256, 0, stream>>>((const float4*)x, (ushort4*)xh, n4);
    k_prep_w<<<32, 256, 0, stream>>>(Wl1, Wr1, wt1);
    k_prep_w<<<32, 256, 0, stream>>>(Wl2, Wr2, wt2);

    // graph build: two-level LDS counting sort, zero global atomics
    k_p1_hist<<<P1B, 256, 0, stream>>>(dst, hist);
    k_bin_total<<<NBUCK, 256, 0, stream>>>(hist, bin_total);
    k_bin_base<<<1, 512, 0, stream>>>(bin_total, bucket_start, offsets);
    k_cursor_base<<<NBUCK, 512, 0, stream>>>(hist, bucket_start);
    k_p1_scatter<<<P1B, 256, 0, stream>>>(src, dst, hist, pairs);
    k_bucket_csr<<<NBUCK, 256, 0, stream>>>(pairs, bucket_start, ssrc, offsets, inv_deg);

    // layer 1: gather f16 x -> aggh (f16), MFMA dual GEMM -> h1h (f16)
    k_aggregate<<<(NN + 3) / 4, 256, 0, stream>>>((const uint4*)xh, ssrc, offsets, inv_deg, (uint4*)aggh);
    k_linear<false><<<tile, 256, 0, stream>>>((const uint4*)aggh, (const uint4*)xh, (const uint4*)wt1,
                                              bl1, Wfc, bfc, nullptr, h1h);
    // layer 2 + fused head
    k_aggregate<<<(NN + 3) / 4, 256, 0, stream>>>((const uint4*)h1h, ssrc, offsets, inv_deg, (uint4*)aggh);
    k_linear<true><<<tile, 256, 0, stream>>>((const uint4*)aggh, (const uint4*)h1h, (const uint4*)wt2,
                                             bl2, Wfc, bfc, out, nullptr);
}